// Round 14
// baseline (147.947 us; speedup 1.0000x reference)
//
#include <hip/hip_runtime.h>
#include <hip/hip_bf16.h>
#include <math.h>

#define BATCH 64
#define TT 512
#define HH 1024
#define KK 8
#define ROWS (BATCH * TT)          // 32768
#define SEG  (ROWS * KK)           // 262144 floats per logits output
#define TAGS_OFF (3 * SEG)         // 786432
#define LOSS_OFF (TAGS_OFF + BATCH * 3 * TT)  // 884736
#define HIST_FLOATS (192 * TT * KK)           // 786432 floats (3 MB)
#define LPART_OFF (1 << 20)                   // floats; partials at ws + 4 MB

// ---------------------------------------------------------------------------
// Kernel 1: fused 3-head GEMM (R11-R13, ~33 us at its DS floor; FROZEN).
// ---------------------------------------------------------------------------
__global__ __launch_bounds__(256, 2) void gemm_heads(
    const float* __restrict__ enc,
    const float* __restrict__ Wt, const float* __restrict__ bt,
    const float* __restrict__ Wp, const float* __restrict__ bpv,
    const float* __restrict__ Wm, const float* __restrict__ bm,
    float* __restrict__ out)
{
    __shared__ float xt[4][2][16][68];
    __shared__ float wl[4][2][16][32];
    __shared__ float biasl[24];

    int tid  = threadIdx.x;
    int lane = tid & 63;
    int w    = __builtin_amdgcn_readfirstlane(tid >> 6);
    int r    = lane >> 2;
    int q    = lane & 3;
    int rowblk = blockIdx.x * 64;

    if (tid < 24) {
        int hd = tid >> 3, cl = tid & 7;
        biasl[tid] = (hd == 0) ? bt[cl] : (hd == 1) ? bpv[cl] : bm[cl];
    }

    const float* encw = enc + (size_t)rowblk * HH + w * 256;
    const float* Wkt = Wt + w * 2048;
    const float* Wkp = Wp + w * 2048;
    const float* Wkm = Wm + w * 2048;

    int srow = lane >> 2;
    int schunk = lane & 3;

    float acc[24];
#pragma unroll
    for (int c = 0; c < 24; ++c) acc[c] = 0.f;

    float4 sreg[4];
    float  wreg[6];

#define LOADT(it)                                                             \
    {                                                                         \
        _Pragma("unroll")                                                     \
        for (int i = 0; i < 4; ++i)                                           \
            sreg[i] = *(const float4*)(encw + (size_t)(srow + 16 * i) * HH +  \
                                       (it) * 16 + schunk * 4);               \
    }
#define WRITET(buf)                                                           \
    {                                                                         \
        _Pragma("unroll")                                                     \
        for (int i = 0; i < 4; ++i) {                                         \
            xt[w][buf][schunk * 4 + 0][srow + 16 * i] = sreg[i].x;            \
            xt[w][buf][schunk * 4 + 1][srow + 16 * i] = sreg[i].y;            \
            xt[w][buf][schunk * 4 + 2][srow + 16 * i] = sreg[i].z;            \
            xt[w][buf][schunk * 4 + 3][srow + 16 * i] = sreg[i].w;            \
        }                                                                     \
    }
#define WLOADG(it)                                                            \
    {                                                                         \
        wreg[0] = Wkt[(it) * 128 + lane]; wreg[1] = Wkt[(it) * 128 + 64 + lane]; \
        wreg[2] = Wkp[(it) * 128 + lane]; wreg[3] = Wkp[(it) * 128 + 64 + lane]; \
        wreg[4] = Wkm[(it) * 128 + lane]; wreg[5] = Wkm[(it) * 128 + 64 + lane]; \
    }
#define WWRITE(buf)                                                           \
    {                                                                         \
        int col_ = lane & 7;                                                  \
        _Pragma("unroll")                                                     \
        for (int i = 0; i < 6; ++i) {                                         \
            int hh_ = (lane >> 3) + 8 * (i & 1);                              \
            int c_  = 8 * (i >> 1) + col_;                                    \
            int q_  = (c_ * 43) >> 8;                                         \
            int s_  = c_ - 6 * q_;                                            \
            wl[w][buf][hh_][8 * (q_ ^ (hh_ & 3)) + s_] = wreg[i];             \
        }                                                                     \
    }

    LOADT(0)
    WLOADG(0)
    WRITET(0)
    WWRITE(0)

    for (int it = 0; it < 16; ++it) {
        int cb = it & 1;
        if (it < 15) {
            LOADT(it + 1)
            WLOADG(it + 1)
        }
#pragma unroll
        for (int hh = 0; hh < 16; ++hh) {
            float4 xv = *(const float4*)&xt[w][cb][hh][4 * r];
            const float* wp_ = &wl[w][cb][hh][8 * (q ^ (hh & 3))];
            float4 w0 = *(const float4*)wp_;
            float2 w1 = *(const float2*)(wp_ + 4);
#pragma unroll
            for (int j = 0; j < 4; ++j) {
                float xe = (j == 0) ? xv.x : (j == 1) ? xv.y : (j == 2) ? xv.z : xv.w;
                acc[j * 6 + 0] = fmaf(xe, w0.x, acc[j * 6 + 0]);
                acc[j * 6 + 1] = fmaf(xe, w0.y, acc[j * 6 + 1]);
                acc[j * 6 + 2] = fmaf(xe, w0.z, acc[j * 6 + 2]);
                acc[j * 6 + 3] = fmaf(xe, w0.w, acc[j * 6 + 3]);
                acc[j * 6 + 4] = fmaf(xe, w1.x, acc[j * 6 + 4]);
                acc[j * 6 + 5] = fmaf(xe, w1.y, acc[j * 6 + 5]);
            }
        }
        if (it < 15) {
            WRITET(cb ^ 1)
            WWRITE(cb ^ 1)
        }
    }
#undef LOADT
#undef WRITET
#undef WLOADG
#undef WWRITE

    __syncthreads();
    float* xf = &xt[0][0][0][0];
    int myrow = 4 * r;
    if (w != 0) {
        float* sl = xf + w * 1600;
#pragma unroll
        for (int j = 0; j < 4; ++j)
#pragma unroll
            for (int s = 0; s < 6; ++s)
                sl[(myrow + j) * 25 + q * 6 + s] = acc[j * 6 + s];
    }
    __syncthreads();
    if (w == 0) {
#pragma unroll
        for (int j = 0; j < 4; ++j)
#pragma unroll
            for (int s = 0; s < 6; ++s)
                xf[(myrow + j) * 25 + q * 6 + s] =
                    acc[j * 6 + s] + xf[1600 + (myrow + j) * 25 + q * 6 + s]
                                   + xf[3200 + (myrow + j) * 25 + q * 6 + s]
                                   + xf[4800 + (myrow + j) * 25 + q * 6 + s];
    }
    __syncthreads();
#pragma unroll
    for (int i = 0; i < 2; ++i) {
        int flat = tid + 256 * i;
        if (flat < 384) {
            int seg  = flat >> 7;
            int rem  = flat & 127;
            int row  = rem >> 1;
            int half = rem & 1;
            float4 v;
            v.x = xf[row * 25 + seg * 8 + half * 4 + 0] + biasl[seg * 8 + half * 4 + 0];
            v.y = xf[row * 25 + seg * 8 + half * 4 + 1] + biasl[seg * 8 + half * 4 + 1];
            v.z = xf[row * 25 + seg * 8 + half * 4 + 2] + biasl[seg * 8 + half * 4 + 2];
            v.w = xf[row * 25 + seg * 8 + half * 4 + 3] + biasl[seg * 8 + half * 4 + 3];
            *(float4*)(out + (size_t)seg * SEG + (size_t)(rowblk + row) * 8 + half * 4) = v;
        }
    }
}

// ---------------------------------------------------------------------------
// DPP helpers: all within-octet (xor1=quad_perm 0xB1, xor2=0x4E,
// xor7=row_half_mirror 0x141, quad-bcast0=0x00). No permlane, no DS.
// ---------------------------------------------------------------------------
#define DPPF(x, ctrl) __int_as_float(__builtin_amdgcn_update_dpp(              \
    0, __float_as_int(x), ctrl, 0xF, 0xF, true))

// broadcast octet-lane-0's value to the whole octet (3 inst)
__device__ __forceinline__ float bcast8(float x, int lane) {
    float qv = DPPF(x, 0x00);      // quad lane0
    float hv = DPPF(qv, 0x141);    // mirrors quad0's value into upper quad
    return (lane & 4) ? hv : qv;
}

// 7-DPP butterfly all-gather within octet. After call, out[j] = v[p ^ M[j]],
// M = {0,1,2,3,7,6,5,4} (p = lane&7).
#define GATHER8(ao, r0, r1, r2, r3, r4, r5, r6, r7)                            \
    {                                                                          \
        float s1_ = DPPF(ao, 0xB1);                                            \
        float s2_ = DPPF(ao, 0x4E);                                            \
        float s3_ = DPPF(s1_, 0x4E);                                           \
        float s7_ = DPPF(ao, 0x141);                                           \
        float s6_ = DPPF(s1_, 0x141);                                          \
        float s5_ = DPPF(s2_, 0x141);                                          \
        float s4_ = DPPF(s3_, 0x141);                                          \
        r0 = ao; r1 = s1_; r2 = s2_; r3 = s3_;                                 \
        r4 = s7_; r5 = s6_; r6 = s5_; r7 = s4_;                                \
    }

// ---------------------------------------------------------------------------
// Kernel 2: Viterbi forward, values-only. 24 blocks x 64 threads; each wave
// runs 8 sequences (octet per seq, lane p = state kn). Per step: 8 in-lane
// adds + 7-max tree + lt add + 7-DPP gather (~27 inst for 8 seqs). Alpha
// history streamed to ws (fire-and-forget); bp reconstructed later.
// ---------------------------------------------------------------------------
__global__ __launch_bounds__(64) void vit_fwd(
    const float* __restrict__ logits,
    const float* __restrict__ trans_t,
    const float* __restrict__ trans_p,
    const float* __restrict__ trans_m,
    float* __restrict__ hist)
{
    int lane = threadIdx.x;
    int g = lane >> 3, p = lane & 7;
    int bb = blockIdx.x;               // 0..23
    int h  = bb >> 3;                  // 8 blocks per head
    int seq = 8 * bb + g;              // seq = h*64 + b ordering

    const float* TR = (h == 0) ? trans_t : (h == 1) ? trans_p : trans_m;
    const float* Lgp = logits + (size_t)seq * (TT * KK) + p;
    float* hp = hist + (size_t)seq * (TT * KK) + p;

    // permuted T column: Tc[j] = T[p ^ M[j]][p]
    float Tc0 = TR[(p ^ 0) * 8 + p], Tc1 = TR[(p ^ 1) * 8 + p];
    float Tc2 = TR[(p ^ 2) * 8 + p], Tc3 = TR[(p ^ 3) * 8 + p];
    float Tc4 = TR[(p ^ 7) * 8 + p], Tc5 = TR[(p ^ 6) * 8 + p];
    float Tc6 = TR[(p ^ 5) * 8 + p], Tc7 = TR[(p ^ 4) * 8 + p];

    float r0, r1, r2, r3, r4, r5, r6, r7;
    float ao = Lgp[0];                 // alpha_0[p]
    hp[0] = ao;
    GATHER8(ao, r0, r1, r2, r3, r4, r5, r6, r7)

#define VSTEP(t, LT)                                                           \
    {                                                                          \
        float m0 = r0 + Tc0, m1 = r1 + Tc1, m2 = r2 + Tc2, m3 = r3 + Tc3;      \
        float m4 = r4 + Tc4, m5 = r5 + Tc5, m6 = r6 + Tc6, m7 = r7 + Tc7;      \
        float x01 = fmaxf(m0, m1), x23 = fmaxf(m2, m3);                        \
        float x45 = fmaxf(m4, m5), x67 = fmaxf(m6, m7);                        \
        float vmax = fmaxf(fmaxf(x01, x23), fmaxf(x45, x67));                  \
        float ao_ = vmax + (LT);                                               \
        hp[(t) * 8] = ao_;                                                     \
        GATHER8(ao_, r0, r1, r2, r3, r4, r5, r6, r7)                           \
    }

    // 4-slot lt prefetch (reads past t=511 land in the next seq's row /
    // in-bounds d_out; values unused)
    float l0 = Lgp[8 * 1], l1 = Lgp[8 * 2], l2 = Lgp[8 * 3], l3 = Lgp[8 * 4];
    for (int kk = 0; kk < 127; ++kk) {
        int t = 1 + 4 * kk;
        VSTEP(t, l0)     l0 = Lgp[8 * (t + 4)];
        VSTEP(t + 1, l1) l1 = Lgp[8 * (t + 5)];
        VSTEP(t + 2, l2) l2 = Lgp[8 * (t + 6)];
        VSTEP(t + 3, l3) l3 = Lgp[8 * (t + 7)];
    }
    VSTEP(509, l0)
    VSTEP(510, l1)
    VSTEP(511, l2)
#undef VSTEP
}

// ---------------------------------------------------------------------------
// Kernel 3: CRF LSE forward (multiplicative). Same 8-seq/wave layout.
// S[kn] linear-space; step: S' = (sum_j r_j * E_j) * exp(lt); renorm every
// 4 steps via octet-bcast + log (loss tolerance >> renorm rounding).
// Also computes emit+trans scores and writes per-seq partials.
// ---------------------------------------------------------------------------
__global__ __launch_bounds__(64) void lse_fwd(
    const float* __restrict__ logits,
    const int* __restrict__ labels,
    const int* __restrict__ lens,
    const float* __restrict__ trans_t,
    const float* __restrict__ trans_p,
    const float* __restrict__ trans_m,
    float* __restrict__ partial)
{
    int lane = threadIdx.x;
    int g = lane >> 3, p = lane & 7;
    int bb = blockIdx.x;
    int h  = bb >> 3;
    int seq = 8 * bb + g;
    int b   = seq & 63;

    const float* TR = (h == 0) ? trans_t : (h == 1) ? trans_p : trans_m;
    const float* Lgp = logits + (size_t)seq * (TT * KK) + p;
    int len = lens[b];

    float E0 = __expf(TR[(p ^ 0) * 8 + p]), E1 = __expf(TR[(p ^ 1) * 8 + p]);
    float E2 = __expf(TR[(p ^ 2) * 8 + p]), E3 = __expf(TR[(p ^ 3) * 8 + p]);
    float E4 = __expf(TR[(p ^ 7) * 8 + p]), E5 = __expf(TR[(p ^ 6) * 8 + p]);
    float E6 = __expf(TR[(p ^ 5) * 8 + p]), E7 = __expf(TR[(p ^ 4) * 8 + p]);

    float a0 = Lgp[0];
    float c0 = bcast8(a0, lane);
    float S  = __expf(a0 - c0);
    float Mc = c0;
    float r0, r1, r2, r3, r4, r5, r6, r7;
    GATHER8(S, r0, r1, r2, r3, r4, r5, r6, r7)

#define LSTEP(t, LT, RENORM)                                                   \
    {                                                                          \
        float p0 = r0 * E0, p1 = r1 * E1, p2 = r2 * E2, p3 = r3 * E3;          \
        float p4 = r4 * E4, p5 = r5 * E5, p6 = r6 * E6, p7 = r7 * E7;          \
        float ss = ((p0 + p1) + (p2 + p3)) + ((p4 + p5) + (p6 + p7));          \
        float Sn = ss * __expf(LT);                                            \
        S = ((t) < len) ? Sn : S;                                              \
        if (RENORM) {                                                          \
            float sref = bcast8(S, lane);                                      \
            float gg = __logf(sref);                                           \
            S *= __expf(-gg);                                                  \
            Mc += gg;                                                          \
        }                                                                      \
        GATHER8(S, r0, r1, r2, r3, r4, r5, r6, r7)                             \
    }

    float l0 = Lgp[8 * 1], l1 = Lgp[8 * 2], l2 = Lgp[8 * 3], l3 = Lgp[8 * 4];
    for (int kk = 0; kk < 127; ++kk) {
        int t = 1 + 4 * kk;
        LSTEP(t, l0, 1)      l0 = Lgp[8 * (t + 4)];
        LSTEP(t + 1, l1, 0)  l1 = Lgp[8 * (t + 5)];
        LSTEP(t + 2, l2, 0)  l2 = Lgp[8 * (t + 6)];
        LSTEP(t + 3, l3, 0)  l3 = Lgp[8 * (t + 7)];
    }
    LSTEP(509, l0, 1)
    LSTEP(510, l1, 0)
    LSTEP(511, l2, 0)
#undef LSTEP

    // logZ = Mc + log(sum over states)  (r_j = full final S vector, permuted)
    float sum8 = ((r0 + r1) + (r2 + r3)) + ((r4 + r5) + (r6 + r7));
    float logZ = Mc + __logf(sum8);

    // emit + transition scores: 8 lanes per seq, lane p covers t = p + 8j
    const float* Lg = logits + (size_t)seq * (TT * KK);
    const int* lab = labels + b * (3 * TT) + h * TT;
    int off = h * 8;
    float sc = 0.f;
    for (int j = 0; j < 64; ++j) {
        int t = p + 8 * j;
        if (t < len) {
            int tg = lab[t] - off;
            sc += Lg[t * 8 + tg];
            if (t >= 1) {
                int tp = lab[t - 1] - off;
                sc += TR[tp * 8 + tg];
            }
        }
    }
    sc += DPPF(sc, 0xB1);
    sc += DPPF(sc, 0x4E);
    sc += DPPF(sc, 0x141);

    if (p == 0) partial[seq] = logZ - sc;
}

// ---------------------------------------------------------------------------
// Kernel 4: bp reconstruction (parallel, bit-exact: same floats, ordered-kp
// scan = min-index ties) + chunked backtrack. 192 blocks x 64 threads.
// ---------------------------------------------------------------------------
__global__ __launch_bounds__(64) void vit_bt(
    const float* __restrict__ hist,
    const float* __restrict__ trans_t,
    const float* __restrict__ trans_p,
    const float* __restrict__ trans_m,
    float* __restrict__ out_tags)
{
    __shared__ unsigned bpw[TT * 2];       // 4 KB backpointers
    __shared__ unsigned fmapw[64][2];
    __shared__ unsigned char bnd[64];

    int seq = blockIdx.x;
    int h = seq >> 6, b = seq & 63;
    int lane = threadIdx.x;
    int c = lane >> 3, kn = lane & 7;
    unsigned char* bpb = (unsigned char*)bpw;

    const float* TR = (h == 0) ? trans_t : (h == 1) ? trans_p : trans_m;
    const float* H = hist + (size_t)seq * (TT * KK);

    float T0 = TR[0 * 8 + kn], T1 = TR[1 * 8 + kn], T2 = TR[2 * 8 + kn];
    float T3 = TR[3 * 8 + kn], T4 = TR[4 * 8 + kn], T5 = TR[5 * 8 + kn];
    float T6 = TR[6 * 8 + kn], T7 = TR[7 * 8 + kn];

    for (int j = 0; j < 64; ++j) {
        int t = c * 64 + j + 1;
        if (t <= 511) {
            float4 a03 = *(const float4*)&H[(t - 1) * 8];
            float4 a47 = *(const float4*)&H[(t - 1) * 8 + 4];
            float v = a03.x + T0; int vi = 0; float nv;
            nv = a03.y + T1; if (nv > v) { v = nv; vi = 1; }
            nv = a03.z + T2; if (nv > v) { v = nv; vi = 2; }
            nv = a03.w + T3; if (nv > v) { v = nv; vi = 3; }
            nv = a47.x + T4; if (nv > v) { v = nv; vi = 4; }
            nv = a47.y + T5; if (nv > v) { v = nv; vi = 5; }
            nv = a47.z + T6; if (nv > v) { v = nv; vi = 6; }
            nv = a47.w + T7; if (nv > v) { v = nv; vi = 7; }
            bpb[t * 8 + kn] = (unsigned char)vi;
        }
    }

    // last = argmax of final alpha (in-lane ordered scan; same in all lanes)
    float4 f03 = *(const float4*)&H[511 * 8];
    float4 f47 = *(const float4*)&H[511 * 8 + 4];
    float fv = f03.x; int last_ = 0; float nf;
    nf = f03.y; if (nf > fv) { fv = nf; last_ = 1; }
    nf = f03.z; if (nf > fv) { fv = nf; last_ = 2; }
    nf = f03.w; if (nf > fv) { fv = nf; last_ = 3; }
    nf = f47.x; if (nf > fv) { fv = nf; last_ = 4; }
    nf = f47.y; if (nf > fv) { fv = nf; last_ = 5; }
    nf = f47.z; if (nf > fv) { fv = nf; last_ = 6; }
    nf = f47.w; if (nf > fv) { fv = nf; last_ = 7; }

    asm volatile("" ::: "memory");   // same-wave DS order (proven pattern)

    // Phase A: lane l composes bp maps for t in [8l+1, 8l+8]
    int t0 = lane * 8;
    unsigned rw[16];
#pragma unroll
    for (int j = 0; j < 8; ++j) {
        int t = t0 + 1 + j;
        if (t <= 511) { rw[2 * j] = bpw[t * 2]; rw[2 * j + 1] = bpw[t * 2 + 1]; }
        else          { rw[2 * j] = 0x03020100u; rw[2 * j + 1] = 0x07060504u; }
    }
    unsigned sv[8];
#pragma unroll
    for (int i = 0; i < 8; ++i) sv[i] = i;
#pragma unroll
    for (int j = 7; j >= 0; --j) {
        unsigned d0 = rw[2 * j], d1 = rw[2 * j + 1];
#pragma unroll
        for (int i = 0; i < 8; ++i) {
            unsigned s = sv[i];
            unsigned d = (s < 4) ? d0 : d1;
            sv[i] = (d >> (8 * (s & 3))) & 0xffu;
        }
    }
    fmapw[lane][0] = sv[0] | (sv[1] << 8) | (sv[2] << 16) | (sv[3] << 24);
    fmapw[lane][1] = sv[4] | (sv[5] << 8) | (sv[6] << 16) | (sv[7] << 24);
    asm volatile("" ::: "memory");

    if (lane == 0) {
        unsigned cur = (unsigned)last_;
        for (int l = 63; l >= 0; --l) {
            unsigned d = (cur < 4) ? fmapw[l][0] : fmapw[l][1];
            cur = (d >> (8 * (cur & 3))) & 0xffu;
            bnd[l] = (unsigned char)cur;
        }
    }
    asm volatile("" ::: "memory");

    int off = h * 8;
    float* otag = out_tags + b * (3 * TT) + h * TT;
    unsigned curr = (lane == 63) ? (unsigned)last_ : (unsigned)bnd[lane + 1];
#pragma unroll
    for (int j = 7; j >= 0; --j) {
        unsigned d = (curr < 4) ? rw[2 * j] : rw[2 * j + 1];
        curr = (d >> (8 * (curr & 3))) & 0xffu;
        otag[t0 + j] = (float)((int)curr + off);
    }
}

// ---------------------------------------------------------------------------
// Kernel 5: deterministic loss reduction (192 partials -> scalar)
// ---------------------------------------------------------------------------
__global__ __launch_bounds__(64) void loss_reduce(
    const float* __restrict__ partial, float* __restrict__ out_loss)
{
    int lane = threadIdx.x;
    float s = partial[lane] + partial[lane + 64] + partial[lane + 128];
#pragma unroll
    for (int d = 1; d <= 32; d <<= 1) s += __shfl_xor(s, d);
    if (lane == 0) *out_loss = s;
}

// ---------------------------------------------------------------------------
extern "C" void kernel_launch(void* const* d_in, const int* in_sizes, int n_in,
                              void* d_out, int out_size, void* d_ws, size_t ws_size,
                              hipStream_t stream) {
    const float* enc    = (const float*)d_in[0];
    const int*   labels = (const int*)d_in[1];
    const int*   lens   = (const int*)d_in[2];
    const float* Wt     = (const float*)d_in[3];
    const float* bt     = (const float*)d_in[4];
    const float* Wp     = (const float*)d_in[5];
    const float* bpv    = (const float*)d_in[6];
    const float* Wm     = (const float*)d_in[7];
    const float* bm     = (const float*)d_in[8];
    const float* tr_t   = (const float*)d_in[9];
    const float* tr_p   = (const float*)d_in[10];
    const float* tr_m   = (const float*)d_in[11];

    float* out  = (float*)d_out;
    float* hist = (float*)d_ws;                    // 3 MB alpha history
    float* lpart = (float*)d_ws + LPART_OFF;       // 192 partials @ +4 MB

    gemm_heads<<<ROWS / 64, 256, 0, stream>>>(enc, Wt, bt, Wp, bpv, Wm, bm, out);
    vit_fwd<<<24, 64, 0, stream>>>(out, tr_t, tr_p, tr_m, hist);
    lse_fwd<<<24, 64, 0, stream>>>(out, labels, lens, tr_t, tr_p, tr_m, lpart);
    vit_bt<<<192, 64, 0, stream>>>(hist, tr_t, tr_p, tr_m, out + TAGS_OFF);
    loss_reduce<<<1, 64, 0, stream>>>(lpart, out + LOSS_OFF);
}

// Round 15
// 73.799 us; speedup vs baseline: 2.0047x; 2.0047x over previous
//
#include <hip/hip_runtime.h>
#include <hip/hip_bf16.h>
#include <math.h>

#define BATCH 64
#define TT 512
#define HH 1024
#define KK 8
#define ROWS (BATCH * TT)          // 32768
#define SEG  (ROWS * KK)           // 262144 floats per logits output
#define TAGS_OFF (3 * SEG)         // 786432
#define LOSS_OFF (TAGS_OFF + BATCH * 3 * TT)  // 884736

// ---------------------------------------------------------------------------
// Kernel 1: fused 3-head GEMM (R11-R13, ~33 us at its DS floor; FROZEN).
// ---------------------------------------------------------------------------
__global__ __launch_bounds__(256, 2) void gemm_heads(
    const float* __restrict__ enc,
    const float* __restrict__ Wt, const float* __restrict__ bt,
    const float* __restrict__ Wp, const float* __restrict__ bpv,
    const float* __restrict__ Wm, const float* __restrict__ bm,
    float* __restrict__ out)
{
    __shared__ float xt[4][2][16][68];
    __shared__ float wl[4][2][16][32];
    __shared__ float biasl[24];

    int tid  = threadIdx.x;
    int lane = tid & 63;
    int w    = __builtin_amdgcn_readfirstlane(tid >> 6);
    int r    = lane >> 2;
    int q    = lane & 3;
    int rowblk = blockIdx.x * 64;

    if (tid < 24) {
        int hd = tid >> 3, cl = tid & 7;
        biasl[tid] = (hd == 0) ? bt[cl] : (hd == 1) ? bpv[cl] : bm[cl];
    }

    const float* encw = enc + (size_t)rowblk * HH + w * 256;
    const float* Wkt = Wt + w * 2048;
    const float* Wkp = Wp + w * 2048;
    const float* Wkm = Wm + w * 2048;

    int srow = lane >> 2;
    int schunk = lane & 3;

    float acc[24];
#pragma unroll
    for (int c = 0; c < 24; ++c) acc[c] = 0.f;

    float4 sreg[4];
    float  wreg[6];

#define LOADT(it)                                                             \
    {                                                                         \
        _Pragma("unroll")                                                     \
        for (int i = 0; i < 4; ++i)                                           \
            sreg[i] = *(const float4*)(encw + (size_t)(srow + 16 * i) * HH +  \
                                       (it) * 16 + schunk * 4);               \
    }
#define WRITET(buf)                                                           \
    {                                                                         \
        _Pragma("unroll")                                                     \
        for (int i = 0; i < 4; ++i) {                                         \
            xt[w][buf][schunk * 4 + 0][srow + 16 * i] = sreg[i].x;            \
            xt[w][buf][schunk * 4 + 1][srow + 16 * i] = sreg[i].y;            \
            xt[w][buf][schunk * 4 + 2][srow + 16 * i] = sreg[i].z;            \
            xt[w][buf][schunk * 4 + 3][srow + 16 * i] = sreg[i].w;            \
        }                                                                     \
    }
#define WLOADG(it)                                                            \
    {                                                                         \
        wreg[0] = Wkt[(it) * 128 + lane]; wreg[1] = Wkt[(it) * 128 + 64 + lane]; \
        wreg[2] = Wkp[(it) * 128 + lane]; wreg[3] = Wkp[(it) * 128 + 64 + lane]; \
        wreg[4] = Wkm[(it) * 128 + lane]; wreg[5] = Wkm[(it) * 128 + 64 + lane]; \
    }
#define WWRITE(buf)                                                           \
    {                                                                         \
        int col_ = lane & 7;                                                  \
        _Pragma("unroll")                                                     \
        for (int i = 0; i < 6; ++i) {                                         \
            int hh_ = (lane >> 3) + 8 * (i & 1);                              \
            int c_  = 8 * (i >> 1) + col_;                                    \
            int q_  = (c_ * 43) >> 8;                                         \
            int s_  = c_ - 6 * q_;                                            \
            wl[w][buf][hh_][8 * (q_ ^ (hh_ & 3)) + s_] = wreg[i];             \
        }                                                                     \
    }

    LOADT(0)
    WLOADG(0)
    WRITET(0)
    WWRITE(0)

    for (int it = 0; it < 16; ++it) {
        int cb = it & 1;
        if (it < 15) {
            LOADT(it + 1)
            WLOADG(it + 1)
        }
#pragma unroll
        for (int hh = 0; hh < 16; ++hh) {
            float4 xv = *(const float4*)&xt[w][cb][hh][4 * r];
            const float* wp_ = &wl[w][cb][hh][8 * (q ^ (hh & 3))];
            float4 w0 = *(const float4*)wp_;
            float2 w1 = *(const float2*)(wp_ + 4);
#pragma unroll
            for (int j = 0; j < 4; ++j) {
                float xe = (j == 0) ? xv.x : (j == 1) ? xv.y : (j == 2) ? xv.z : xv.w;
                acc[j * 6 + 0] = fmaf(xe, w0.x, acc[j * 6 + 0]);
                acc[j * 6 + 1] = fmaf(xe, w0.y, acc[j * 6 + 1]);
                acc[j * 6 + 2] = fmaf(xe, w0.z, acc[j * 6 + 2]);
                acc[j * 6 + 3] = fmaf(xe, w0.w, acc[j * 6 + 3]);
                acc[j * 6 + 4] = fmaf(xe, w1.x, acc[j * 6 + 4]);
                acc[j * 6 + 5] = fmaf(xe, w1.y, acc[j * 6 + 5]);
            }
        }
        if (it < 15) {
            WRITET(cb ^ 1)
            WWRITE(cb ^ 1)
        }
    }
#undef LOADT
#undef WRITET
#undef WLOADG
#undef WWRITE

    __syncthreads();
    float* xf = &xt[0][0][0][0];
    int myrow = 4 * r;
    if (w != 0) {
        float* sl = xf + w * 1600;
#pragma unroll
        for (int j = 0; j < 4; ++j)
#pragma unroll
            for (int s = 0; s < 6; ++s)
                sl[(myrow + j) * 25 + q * 6 + s] = acc[j * 6 + s];
    }
    __syncthreads();
    if (w == 0) {
#pragma unroll
        for (int j = 0; j < 4; ++j)
#pragma unroll
            for (int s = 0; s < 6; ++s)
                xf[(myrow + j) * 25 + q * 6 + s] =
                    acc[j * 6 + s] + xf[1600 + (myrow + j) * 25 + q * 6 + s]
                                   + xf[3200 + (myrow + j) * 25 + q * 6 + s]
                                   + xf[4800 + (myrow + j) * 25 + q * 6 + s];
    }
    __syncthreads();
#pragma unroll
    for (int i = 0; i < 2; ++i) {
        int flat = tid + 256 * i;
        if (flat < 384) {
            int seg  = flat >> 7;
            int rem  = flat & 127;
            int row  = rem >> 1;
            int half = rem & 1;
            float4 v;
            v.x = xf[row * 25 + seg * 8 + half * 4 + 0] + biasl[seg * 8 + half * 4 + 0];
            v.y = xf[row * 25 + seg * 8 + half * 4 + 1] + biasl[seg * 8 + half * 4 + 1];
            v.z = xf[row * 25 + seg * 8 + half * 4 + 2] + biasl[seg * 8 + half * 4 + 2];
            v.w = xf[row * 25 + seg * 8 + half * 4 + 3] + biasl[seg * 8 + half * 4 + 3];
            *(float4*)(out + (size_t)seg * SEG + (size_t)(rowblk + row) * 8 + half * 4) = v;
        }
    }
}

// ---------------------------------------------------------------------------
// Pure-VALU cross-lane helpers
// ---------------------------------------------------------------------------
#define DPPF(x, ctrl) __int_as_float(__builtin_amdgcn_update_dpp(              \
    0, __float_as_int(x), ctrl, 0xF, 0xF, true))
#define SWIZF(x, pat) __int_as_float(__builtin_amdgcn_ds_swizzle(              \
    __float_as_int(x), pat))
#define BPERMF(a, x)  __int_as_float(__builtin_amdgcn_ds_bpermute(             \
    a, __float_as_int(x)))

__device__ __forceinline__ float rfl(float x) {
    return __int_as_float(__builtin_amdgcn_readfirstlane(__float_as_int(x)));
}

#if __has_builtin(__builtin_amdgcn_permlane16_swap)
__device__ __forceinline__ float xor16f(float x, int lane) {
    typedef unsigned uv2 __attribute__((ext_vector_type(2)));
    uv2 r = __builtin_amdgcn_permlane16_swap(__float_as_uint(x), __float_as_uint(x), false, false);
    return __uint_as_float((lane & 16) ? r.x : r.y);
}
#else
__device__ __forceinline__ float xor16f(float x, int lane) { return SWIZF(x, 0x401F); }
#endif

#if __has_builtin(__builtin_amdgcn_permlane32_swap)
__device__ __forceinline__ float xor32f(float x, int lane) {
    typedef unsigned uv2 __attribute__((ext_vector_type(2)));
    uv2 r = __builtin_amdgcn_permlane32_swap(__float_as_uint(x), __float_as_uint(x), false, false);
    return __uint_as_float((lane & 32) ? r.x : r.y);
}
#else
__device__ __forceinline__ float xor32f(float x, int lane) {
    return BPERMF(((lane ^ 32) << 2), x);
}
#endif

// ---------------------------------------------------------------------------
// Kernel 2: 192 blocks x 128 threads (2 waves, 1 seq/block). R13 structure
// with CHUNKED lt loads: per 32 steps, issue 32 independent ds_read_b32 into
// named registers, then sched_barrier(0) pins them BEFORE the 32-step VALU
// recurrence (defeats the compiler's load-sinking that serialized ~120-cyc
// LDS latency into every iteration -- the R14/R12 triangulated bind).
// ---------------------------------------------------------------------------
__global__ __launch_bounds__(128) void crf_vit(
    const float* __restrict__ logits,
    const int* __restrict__ labels,
    const int* __restrict__ lens,
    const float* __restrict__ trans_t,
    const float* __restrict__ trans_p,
    const float* __restrict__ trans_m,
    float* __restrict__ out_tags,
    float* __restrict__ partial)
{
    __shared__ float llds[TT * KK];               // 16 KB logits
    __shared__ __align__(16) float alds[TT * KK]; // 16 KB alpha history
    __shared__ unsigned bpw[TT * 2];              // 4 KB backpointers
    __shared__ unsigned fmapw[64][2];
    __shared__ unsigned char bnd[64];

    int blk = blockIdx.x;
    int h   = blk >> 6;
    int b   = blk & 63;
    int tid = threadIdx.x;
    int wid = __builtin_amdgcn_readfirstlane(tid >> 6);
    int lane = tid & 63;
    int hi = lane >> 3, lo = lane & 7;
    unsigned char* bpb = (unsigned char*)bpw;

    const float* L = logits + ((size_t)h * BATCH + b) * (TT * KK);
    const float4* Lv = (const float4*)L;
    float4* lv = (float4*)llds;
#pragma unroll
    for (int i = 0; i < 8; ++i) lv[tid + 128 * i] = Lv[tid + 128 * i];
    __syncthreads();

    const float* TR = (h == 0) ? trans_t : (h == 1) ? trans_p : trans_m;
    int len = lens[b];
    float trA = TR[lo * 8 + hi];   // even step: kp=lo -> kn=hi
    float trB = TR[hi * 8 + lo];   // odd step:  kp=hi -> kn=lo

    if (wid == 0) {
        // ============ Viterbi wave: values-only forward, chunked ============
        float av = llds[lo];
        if (lane < 8) alds[lane] = llds[lane];    // alpha_0

#define VSTEP_EVEN(t, LT)                                                      \
    {                                                                          \
        float v0 = av + trA;                                                   \
        float ra = fmaxf(v0, DPPF(v0, 0xB1));                                  \
        float rb = fmaxf(ra, DPPF(ra, 0x4E));                                  \
        float vmax = fmaxf(rb, DPPF(rb, 0x141));                               \
        av = vmax + (LT);                                                      \
        if (lo == 0) alds[(t) * 8 + hi] = av;                                  \
    }
#define VSTEP_ODD(t, LT)                                                       \
    {                                                                          \
        float v0 = av + trB;                                                   \
        float ra = fmaxf(v0, DPPF(v0, 0x128));                                 \
        float rb = fmaxf(ra, xor16f(ra, lane));                                \
        float vmax = fmaxf(rb, xor32f(rb, lane));                              \
        av = vmax + (LT);                                                      \
        if (hi == 0) alds[(t) * 8 + lo] = av;                                  \
    }

        for (int c = 0; c < 15; ++c) {          // full chunks: t in [1+32c, 32+32c]
            int tb = 1 + 32 * c;
            float lE[16], lO[16];
#pragma unroll
            for (int j = 0; j < 16; ++j) {
                lE[j] = llds[(tb + 2 * j) * 8 + hi];
                lO[j] = llds[(tb + 1 + 2 * j) * 8 + lo];
            }
            __builtin_amdgcn_sched_barrier(0);  // loads stay ABOVE the compute
#pragma unroll
            for (int j = 0; j < 16; ++j) {
                VSTEP_EVEN(tb + 2 * j, lE[j])
                VSTEP_ODD(tb + 2 * j + 1, lO[j])
            }
        }
        {   // epilogue chunk: t = 481..511 (16 even-parity, 15 odd-parity)
            float lE[16], lO[15];
#pragma unroll
            for (int j = 0; j < 16; ++j) lE[j] = llds[(481 + 2 * j) * 8 + hi];
#pragma unroll
            for (int j = 0; j < 15; ++j) lO[j] = llds[(482 + 2 * j) * 8 + lo];
            __builtin_amdgcn_sched_barrier(0);
#pragma unroll
            for (int j = 0; j < 15; ++j) {
                VSTEP_EVEN(481 + 2 * j, lE[j])
                VSTEP_ODD(482 + 2 * j, lO[j])
            }
            VSTEP_EVEN(511, lE[15])
        }
#undef VSTEP_EVEN
#undef VSTEP_ODD

        // last = argmax over final alpha (indexed by hi, replicated over lo)
        float ra = fmaxf(av, DPPF(av, 0x128));
        float rb = fmaxf(ra, xor16f(ra, lane));
        float vmax = fmaxf(rb, xor32f(rb, lane));
        unsigned long long mk = __ballot(av == vmax);
        int last_ = __builtin_ctzll(mk) >> 3;

        asm volatile("" ::: "memory");

        // ---- parallel bp reconstruction from alpha history (bit-exact) ----
        {
            int c = lane >> 3;                    // t-chunk 0..7
            int kn = lane & 7;
            float Tk0 = TR[0 * 8 + kn], Tk1 = TR[1 * 8 + kn];
            float Tk2 = TR[2 * 8 + kn], Tk3 = TR[3 * 8 + kn];
            float Tk4 = TR[4 * 8 + kn], Tk5 = TR[5 * 8 + kn];
            float Tk6 = TR[6 * 8 + kn], Tk7 = TR[7 * 8 + kn];
            for (int j = 0; j < 64; ++j) {
                int t = c * 64 + j + 1;
                if (t <= 511) {
                    float4 a03 = *(const float4*)&alds[(t - 1) * 8];
                    float4 a47 = *(const float4*)&alds[(t - 1) * 8 + 4];
                    float v = a03.x + Tk0; int vi = 0; float nv;
                    nv = a03.y + Tk1; if (nv > v) { v = nv; vi = 1; }
                    nv = a03.z + Tk2; if (nv > v) { v = nv; vi = 2; }
                    nv = a03.w + Tk3; if (nv > v) { v = nv; vi = 3; }
                    nv = a47.x + Tk4; if (nv > v) { v = nv; vi = 4; }
                    nv = a47.y + Tk5; if (nv > v) { v = nv; vi = 5; }
                    nv = a47.z + Tk6; if (nv > v) { v = nv; vi = 6; }
                    nv = a47.w + Tk7; if (nv > v) { v = nv; vi = 7; }
                    bpb[t * 8 + kn] = (unsigned char)vi;
                }
            }
        }
        asm volatile("" ::: "memory");

        // Phase A: lane l composes bp maps for t in [8l+1, 8l+8]
        int t0 = lane * 8;
        unsigned rw[16];
#pragma unroll
        for (int j = 0; j < 8; ++j) {
            int t = t0 + 1 + j;
            if (t <= 511) { rw[2 * j] = bpw[t * 2]; rw[2 * j + 1] = bpw[t * 2 + 1]; }
            else          { rw[2 * j] = 0x03020100u; rw[2 * j + 1] = 0x07060504u; }
        }
        unsigned sv[8];
#pragma unroll
        for (int i = 0; i < 8; ++i) sv[i] = i;
#pragma unroll
        for (int j = 7; j >= 0; --j) {
            unsigned d0 = rw[2 * j], d1 = rw[2 * j + 1];
#pragma unroll
            for (int i = 0; i < 8; ++i) {
                unsigned s = sv[i];
                unsigned d = (s < 4) ? d0 : d1;
                sv[i] = (d >> (8 * (s & 3))) & 0xffu;
            }
        }
        fmapw[lane][0] = sv[0] | (sv[1] << 8) | (sv[2] << 16) | (sv[3] << 24);
        fmapw[lane][1] = sv[4] | (sv[5] << 8) | (sv[6] << 16) | (sv[7] << 24);
        asm volatile("" ::: "memory");

        // Phase B: lane 0 walks 64 chunk maps
        if (lane == 0) {
            unsigned cur = (unsigned)last_;
            for (int l = 63; l >= 0; --l) {
                unsigned d = (cur < 4) ? fmapw[l][0] : fmapw[l][1];
                cur = (d >> (8 * (cur & 3))) & 0xffu;
                bnd[l] = (unsigned char)cur;
            }
        }
        asm volatile("" ::: "memory");

        // Phase C: expand within chunk, write tags
        int off = h * 8;
        float* otag = out_tags + b * (3 * TT) + h * TT;
        unsigned curr = (lane == 63) ? (unsigned)last_ : (unsigned)bnd[lane + 1];
#pragma unroll
        for (int j = 7; j >= 0; --j) {
            unsigned d = (curr < 4) ? rw[2 * j] : rw[2 * j + 1];
            curr = (d >> (8 * (curr & 3))) & 0xffu;
            otag[t0 + j] = (float)((int)curr + off);
        }
    } else {
        // ============ CRF wave: multiplicative logsumexp, chunked ============
        const float LN8 = 2.0794415416798357f;
        float EA = __expf(trA);
        float EB = __expf(trB);
        float al0 = llds[lo];
        float c0 = rfl(al0);
        float S = __expf(al0 - c0);
        float Mc = c0;
        float g = 0.f;

#define LSE_EVEN(t, LT)                                                        \
    {                                                                          \
        float c = rfl(LT) + LN8;                                               \
        float F = __expf((LT) - c);                                            \
        float P = S * EA;                                                      \
        float sa = P + DPPF(P, 0xB1);                                          \
        float sb = sa + DPPF(sa, 0x4E);                                        \
        float ss = sb + DPPF(sb, 0x141);                                       \
        if ((t) < len) { S = ss * F; Mc += c; }                                \
    }
#define LSE_ODD(t, LT)                                                         \
    {                                                                          \
        float c = rfl(LT) + LN8;                                               \
        float F = __expf((LT) - c);                                            \
        float P = S * EB;                                                      \
        float sa = P + DPPF(P, 0x128);                                         \
        float sb = sa + xor16f(sa, lane);                                      \
        float ss = sb + xor32f(sb, lane);                                      \
        if ((t) < len) { S = ss * F; Mc += c; }                                \
    }
#define RENORM4                                                                \
    {                                                                          \
        S *= __expf(-g);                                                       \
        Mc += g;                                                               \
        g = __logf(rfl(S));                                                    \
    }

        for (int c = 0; c < 15; ++c) {
            int tb = 1 + 32 * c;
            float lE[16], lO[16];
#pragma unroll
            for (int j = 0; j < 16; ++j) {
                lE[j] = llds[(tb + 2 * j) * 8 + hi];
                lO[j] = llds[(tb + 1 + 2 * j) * 8 + lo];
            }
            __builtin_amdgcn_sched_barrier(0);
#pragma unroll
            for (int j = 0; j < 16; ++j) {
                if ((j & 1) == 0) RENORM4          // (tb+2j)&3==1 <=> j even
                LSE_EVEN(tb + 2 * j, lE[j])
                LSE_ODD(tb + 2 * j + 1, lO[j])
            }
        }
        {   // epilogue chunk t = 481..511
            float lE[16], lO[15];
#pragma unroll
            for (int j = 0; j < 16; ++j) lE[j] = llds[(481 + 2 * j) * 8 + hi];
#pragma unroll
            for (int j = 0; j < 15; ++j) lO[j] = llds[(482 + 2 * j) * 8 + lo];
            __builtin_amdgcn_sched_barrier(0);
#pragma unroll
            for (int j = 0; j < 15; ++j) {
                if ((j & 1) == 0) RENORM4
                LSE_EVEN(481 + 2 * j, lE[j])
                LSE_ODD(482 + 2 * j, lO[j])
            }
            RENORM4
            LSE_EVEN(511, lE[15])
        }
#undef LSE_EVEN
#undef LSE_ODD
#undef RENORM4

        float aj = Mc + __logf(S);
        float za = fmaxf(aj, DPPF(aj, 0x128));
        float zb = fmaxf(za, xor16f(za, lane));
        float zmax = fmaxf(zb, xor32f(zb, lane));
        float ze = __expf(aj - zmax);
        float zs = ze + DPPF(ze, 0x128);
        float zs2 = zs + xor16f(zs, lane);
        float zsum = zs2 + xor32f(zs2, lane);
        float logZ = zmax + __logf(zsum);

        const int* lab = labels + b * (3 * TT) + h * TT;
        int off = h * 8;
        float sc = 0.f;
#pragma unroll
        for (int j = 0; j < 8; ++j) {
            int t = lane + 64 * j;
            if (t < len) {
                int tg = lab[t] - off;
                sc += llds[t * 8 + tg];
                if (t >= 1) {
                    int tp = lab[t - 1] - off;
                    sc += TR[tp * 8 + tg];
                }
            }
        }
#pragma unroll
        for (int d = 1; d <= 32; d <<= 1) sc += __shfl_xor(sc, d);

        if (lane == 0) partial[blk] = logZ - sc;
    }
}

// ---------------------------------------------------------------------------
// Kernel 3: deterministic loss reduction (192 partials -> scalar)
// ---------------------------------------------------------------------------
__global__ __launch_bounds__(64) void loss_reduce(
    const float* __restrict__ partial, float* __restrict__ out_loss)
{
    int lane = threadIdx.x;
    float s = partial[lane] + partial[lane + 64] + partial[lane + 128];
#pragma unroll
    for (int d = 1; d <= 32; d <<= 1) s += __shfl_xor(s, d);
    if (lane == 0) *out_loss = s;
}

// ---------------------------------------------------------------------------
extern "C" void kernel_launch(void* const* d_in, const int* in_sizes, int n_in,
                              void* d_out, int out_size, void* d_ws, size_t ws_size,
                              hipStream_t stream) {
    const float* enc    = (const float*)d_in[0];
    const int*   labels = (const int*)d_in[1];
    const int*   lens   = (const int*)d_in[2];
    const float* Wt     = (const float*)d_in[3];
    const float* bt     = (const float*)d_in[4];
    const float* Wp     = (const float*)d_in[5];
    const float* bpv    = (const float*)d_in[6];
    const float* Wm     = (const float*)d_in[7];
    const float* bm     = (const float*)d_in[8];
    const float* tr_t   = (const float*)d_in[9];
    const float* tr_p   = (const float*)d_in[10];
    const float* tr_m   = (const float*)d_in[11];

    float* out = (float*)d_out;
    float* lpart = (float*)d_ws;   // 192 floats

    gemm_heads<<<ROWS / 64, 256, 0, stream>>>(enc, Wt, bt, Wp, bpv, Wm, bm, out);
    crf_vit<<<192, 128, 0, stream>>>(out, labels, lens, tr_t, tr_p, tr_m,
                                     out + TAGS_OFF, lpart);
    loss_reduce<<<1, 64, 0, stream>>>(lpart, out + LOSS_OFF);
}

// Round 16
// 70.478 us; speedup vs baseline: 2.0992x; 1.0471x over previous
//
#include <hip/hip_runtime.h>
#include <hip/hip_bf16.h>
#include <math.h>

#define BATCH 64
#define TT 512
#define HH 1024
#define KK 8
#define ROWS (BATCH * TT)          // 32768
#define SEG  (ROWS * KK)           // 262144 floats per logits output
#define TAGS_OFF (3 * SEG)         // 786432
#define LOSS_OFF (TAGS_OFF + BATCH * 3 * TT)  // 884736

// ---------------------------------------------------------------------------
// Kernel 1: fused 3-head GEMM (R11-R15, ~33 us at its DS floor; FROZEN).
// ---------------------------------------------------------------------------
__global__ __launch_bounds__(256, 2) void gemm_heads(
    const float* __restrict__ enc,
    const float* __restrict__ Wt, const float* __restrict__ bt,
    const float* __restrict__ Wp, const float* __restrict__ bpv,
    const float* __restrict__ Wm, const float* __restrict__ bm,
    float* __restrict__ out)
{
    __shared__ float xt[4][2][16][68];
    __shared__ float wl[4][2][16][32];
    __shared__ float biasl[24];

    int tid  = threadIdx.x;
    int lane = tid & 63;
    int w    = __builtin_amdgcn_readfirstlane(tid >> 6);
    int r    = lane >> 2;
    int q    = lane & 3;
    int rowblk = blockIdx.x * 64;

    if (tid < 24) {
        int hd = tid >> 3, cl = tid & 7;
        biasl[tid] = (hd == 0) ? bt[cl] : (hd == 1) ? bpv[cl] : bm[cl];
    }

    const float* encw = enc + (size_t)rowblk * HH + w * 256;
    const float* Wkt = Wt + w * 2048;
    const float* Wkp = Wp + w * 2048;
    const float* Wkm = Wm + w * 2048;

    int srow = lane >> 2;
    int schunk = lane & 3;

    float acc[24];
#pragma unroll
    for (int c = 0; c < 24; ++c) acc[c] = 0.f;

    float4 sreg[4];
    float  wreg[6];

#define LOADT(it)                                                             \
    {                                                                         \
        _Pragma("unroll")                                                     \
        for (int i = 0; i < 4; ++i)                                           \
            sreg[i] = *(const float4*)(encw + (size_t)(srow + 16 * i) * HH +  \
                                       (it) * 16 + schunk * 4);               \
    }
#define WRITET(buf)                                                           \
    {                                                                         \
        _Pragma("unroll")                                                     \
        for (int i = 0; i < 4; ++i) {                                         \
            xt[w][buf][schunk * 4 + 0][srow + 16 * i] = sreg[i].x;            \
            xt[w][buf][schunk * 4 + 1][srow + 16 * i] = sreg[i].y;            \
            xt[w][buf][schunk * 4 + 2][srow + 16 * i] = sreg[i].z;            \
            xt[w][buf][schunk * 4 + 3][srow + 16 * i] = sreg[i].w;            \
        }                                                                     \
    }
#define WLOADG(it)                                                            \
    {                                                                         \
        wreg[0] = Wkt[(it) * 128 + lane]; wreg[1] = Wkt[(it) * 128 + 64 + lane]; \
        wreg[2] = Wkp[(it) * 128 + lane]; wreg[3] = Wkp[(it) * 128 + 64 + lane]; \
        wreg[4] = Wkm[(it) * 128 + lane]; wreg[5] = Wkm[(it) * 128 + 64 + lane]; \
    }
#define WWRITE(buf)                                                           \
    {                                                                         \
        int col_ = lane & 7;                                                  \
        _Pragma("unroll")                                                     \
        for (int i = 0; i < 6; ++i) {                                         \
            int hh_ = (lane >> 3) + 8 * (i & 1);                              \
            int c_  = 8 * (i >> 1) + col_;                                    \
            int q_  = (c_ * 43) >> 8;                                         \
            int s_  = c_ - 6 * q_;                                            \
            wl[w][buf][hh_][8 * (q_ ^ (hh_ & 3)) + s_] = wreg[i];             \
        }                                                                     \
    }

    LOADT(0)
    WLOADG(0)
    WRITET(0)
    WWRITE(0)

    for (int it = 0; it < 16; ++it) {
        int cb = it & 1;
        if (it < 15) {
            LOADT(it + 1)
            WLOADG(it + 1)
        }
#pragma unroll
        for (int hh = 0; hh < 16; ++hh) {
            float4 xv = *(const float4*)&xt[w][cb][hh][4 * r];
            const float* wp_ = &wl[w][cb][hh][8 * (q ^ (hh & 3))];
            float4 w0 = *(const float4*)wp_;
            float2 w1 = *(const float2*)(wp_ + 4);
#pragma unroll
            for (int j = 0; j < 4; ++j) {
                float xe = (j == 0) ? xv.x : (j == 1) ? xv.y : (j == 2) ? xv.z : xv.w;
                acc[j * 6 + 0] = fmaf(xe, w0.x, acc[j * 6 + 0]);
                acc[j * 6 + 1] = fmaf(xe, w0.y, acc[j * 6 + 1]);
                acc[j * 6 + 2] = fmaf(xe, w0.z, acc[j * 6 + 2]);
                acc[j * 6 + 3] = fmaf(xe, w0.w, acc[j * 6 + 3]);
                acc[j * 6 + 4] = fmaf(xe, w1.x, acc[j * 6 + 4]);
                acc[j * 6 + 5] = fmaf(xe, w1.y, acc[j * 6 + 5]);
            }
        }
        if (it < 15) {
            WRITET(cb ^ 1)
            WWRITE(cb ^ 1)
        }
    }
#undef LOADT
#undef WRITET
#undef WLOADG
#undef WWRITE

    __syncthreads();
    float* xf = &xt[0][0][0][0];
    int myrow = 4 * r;
    if (w != 0) {
        float* sl = xf + w * 1600;
#pragma unroll
        for (int j = 0; j < 4; ++j)
#pragma unroll
            for (int s = 0; s < 6; ++s)
                sl[(myrow + j) * 25 + q * 6 + s] = acc[j * 6 + s];
    }
    __syncthreads();
    if (w == 0) {
#pragma unroll
        for (int j = 0; j < 4; ++j)
#pragma unroll
            for (int s = 0; s < 6; ++s)
                xf[(myrow + j) * 25 + q * 6 + s] =
                    acc[j * 6 + s] + xf[1600 + (myrow + j) * 25 + q * 6 + s]
                                   + xf[3200 + (myrow + j) * 25 + q * 6 + s]
                                   + xf[4800 + (myrow + j) * 25 + q * 6 + s];
    }
    __syncthreads();
#pragma unroll
    for (int i = 0; i < 2; ++i) {
        int flat = tid + 256 * i;
        if (flat < 384) {
            int seg  = flat >> 7;
            int rem  = flat & 127;
            int row  = rem >> 1;
            int half = rem & 1;
            float4 v;
            v.x = xf[row * 25 + seg * 8 + half * 4 + 0] + biasl[seg * 8 + half * 4 + 0];
            v.y = xf[row * 25 + seg * 8 + half * 4 + 1] + biasl[seg * 8 + half * 4 + 1];
            v.z = xf[row * 25 + seg * 8 + half * 4 + 2] + biasl[seg * 8 + half * 4 + 2];
            v.w = xf[row * 25 + seg * 8 + half * 4 + 3] + biasl[seg * 8 + half * 4 + 3];
            *(float4*)(out + (size_t)seg * SEG + (size_t)(rowblk + row) * 8 + half * 4) = v;
        }
    }
}

// ---------------------------------------------------------------------------
// Octet DPP helpers (quad_perm + row_half_mirror ONLY -- guaranteed gfx9 DPP;
// no permlane, no swizzle, no bpermute anywhere on the recurrence).
// ---------------------------------------------------------------------------
#define DPPF(x, ctrl) __int_as_float(__builtin_amdgcn_update_dpp(              \
    0, __float_as_int(x), ctrl, 0xF, 0xF, true))

// broadcast octet-lane-0's value to the whole octet (R14-proven)
__device__ __forceinline__ float bcast8(float x, int lane) {
    float qv = DPPF(x, 0x00);      // quad lane0
    float hv = DPPF(qv, 0x141);    // mirror -> other quad sees it
    return (lane & 4) ? hv : qv;
}

// 7-DPP butterfly all-gather within octet (R14-proven).
// After call: r_j = v[p ^ M_j], M = {0,1,2,3,7,6,5,4}, p = lane&7.
#define GATHER8(ao, r0, r1, r2, r3, r4, r5, r6, r7)                            \
    {                                                                          \
        float s1_ = DPPF(ao, 0xB1);                                            \
        float s2_ = DPPF(ao, 0x4E);                                            \
        float s3_ = DPPF(s1_, 0x4E);                                           \
        float s7_ = DPPF(ao, 0x141);                                           \
        float s6_ = DPPF(s1_, 0x141);                                          \
        float s5_ = DPPF(s2_, 0x141);                                          \
        float s4_ = DPPF(s3_, 0x141);                                          \
        r0 = ao; r1 = s1_; r2 = s2_; r3 = s3_;                                 \
        r4 = s7_; r5 = s6_; r6 = s5_; r7 = s4_;                                \
    }

__device__ __forceinline__ float rfl(float x) {
    return __int_as_float(__builtin_amdgcn_readfirstlane(__float_as_int(x)));
}

// ---------------------------------------------------------------------------
// Kernel 2: 192 blocks x 128 threads. Wave 0: Viterbi, octet-replicated state
// (lane p of each octet = state p; per step: GATHER8 + 8 add + 7-max tree +
// lt add -- all VALU), chunked lt loads + sched_barrier (R15-proven), alpha
// history to LDS, parallel bp recon + chunked backtrack (R13-proven).
// Wave 1: multiplicative LSE, same octet layout, F=exp(lt) precomputed per
// chunk (off-chain), renorm every 4 steps.
// ---------------------------------------------------------------------------
__global__ __launch_bounds__(128) void crf_vit(
    const float* __restrict__ logits,
    const int* __restrict__ labels,
    const int* __restrict__ lens,
    const float* __restrict__ trans_t,
    const float* __restrict__ trans_p,
    const float* __restrict__ trans_m,
    float* __restrict__ out_tags,
    float* __restrict__ partial)
{
    __shared__ float llds[TT * KK];               // 16 KB logits
    __shared__ __align__(16) float alds[TT * KK]; // 16 KB alpha history
    __shared__ unsigned bpw[TT * 2];              // 4 KB backpointers
    __shared__ unsigned fmapw[64][2];
    __shared__ unsigned char bnd[64];

    int blk = blockIdx.x;
    int h   = blk >> 6;
    int b   = blk & 63;
    int tid = threadIdx.x;
    int wid = __builtin_amdgcn_readfirstlane(tid >> 6);
    int lane = tid & 63;
    int p = lane & 7;
    unsigned char* bpb = (unsigned char*)bpw;

    const float* L = logits + ((size_t)h * BATCH + b) * (TT * KK);
    const float4* Lv = (const float4*)L;
    float4* lv = (float4*)llds;
#pragma unroll
    for (int i = 0; i < 8; ++i) lv[tid + 128 * i] = Lv[tid + 128 * i];
    __syncthreads();

    const float* TR = (h == 0) ? trans_t : (h == 1) ? trans_p : trans_m;
    int len = lens[b];

    if (wid == 0) {
        // ============ Viterbi wave: octet-replicated, values-only ============
        // Tc_j = T[p ^ M_j][p], matching GATHER8's M
        float Tc0 = TR[(p ^ 0) * 8 + p], Tc1 = TR[(p ^ 1) * 8 + p];
        float Tc2 = TR[(p ^ 2) * 8 + p], Tc3 = TR[(p ^ 3) * 8 + p];
        float Tc4 = TR[(p ^ 7) * 8 + p], Tc5 = TR[(p ^ 6) * 8 + p];
        float Tc6 = TR[(p ^ 5) * 8 + p], Tc7 = TR[(p ^ 4) * 8 + p];

        float av = llds[p];                       // alpha_0 (replicated/octet)
        if (lane < 8) alds[lane] = av;
        float r0, r1, r2, r3, r4, r5, r6, r7;
        GATHER8(av, r0, r1, r2, r3, r4, r5, r6, r7)

#define VSTEP(t, LT)                                                           \
    {                                                                          \
        float m0 = r0 + Tc0, m1 = r1 + Tc1, m2 = r2 + Tc2, m3 = r3 + Tc3;      \
        float m4 = r4 + Tc4, m5 = r5 + Tc5, m6 = r6 + Tc6, m7 = r7 + Tc7;      \
        float x01 = fmaxf(m0, m1), x23 = fmaxf(m2, m3);                        \
        float x45 = fmaxf(m4, m5), x67 = fmaxf(m6, m7);                        \
        av = fmaxf(fmaxf(x01, x23), fmaxf(x45, x67)) + (LT);                   \
        if (lane < 8) alds[(t) * 8 + p] = av;                                  \
        GATHER8(av, r0, r1, r2, r3, r4, r5, r6, r7)                            \
    }

        for (int c = 0; c < 15; ++c) {            // t in [1+32c, 32+32c]
            int tb = 1 + 32 * c;
            float lt[32];
#pragma unroll
            for (int j = 0; j < 32; ++j) lt[j] = llds[(tb + j) * 8 + p];
            __builtin_amdgcn_sched_barrier(0);    // loads stay above compute
#pragma unroll
            for (int j = 0; j < 32; ++j) VSTEP(tb + j, lt[j])
        }
        {   // epilogue: t = 481..511 (31 steps)
            float lt[31];
#pragma unroll
            for (int j = 0; j < 31; ++j) lt[j] = llds[(481 + j) * 8 + p];
            __builtin_amdgcn_sched_barrier(0);
#pragma unroll
            for (int j = 0; j < 31; ++j) VSTEP(481 + j, lt[j])
        }
#undef VSTEP

        asm volatile("" ::: "memory");

        // last = ordered in-lane argmax over final alpha (read back, bcast)
        float4 f03 = *(const float4*)&alds[511 * 8];
        float4 f47 = *(const float4*)&alds[511 * 8 + 4];
        float fv = f03.x; int last_ = 0; float nf;
        nf = f03.y; if (nf > fv) { fv = nf; last_ = 1; }
        nf = f03.z; if (nf > fv) { fv = nf; last_ = 2; }
        nf = f03.w; if (nf > fv) { fv = nf; last_ = 3; }
        nf = f47.x; if (nf > fv) { fv = nf; last_ = 4; }
        nf = f47.y; if (nf > fv) { fv = nf; last_ = 5; }
        nf = f47.z; if (nf > fv) { fv = nf; last_ = 6; }
        nf = f47.w; if (nf > fv) { fv = nf; last_ = 7; }

        // ---- parallel bp reconstruction (bit-exact, ordered-kp scan) ----
        {
            int c = lane >> 3;                    // t-chunk 0..7
            int kn = lane & 7;
            float T0 = TR[0 * 8 + kn], T1 = TR[1 * 8 + kn];
            float T2 = TR[2 * 8 + kn], T3 = TR[3 * 8 + kn];
            float T4 = TR[4 * 8 + kn], T5 = TR[5 * 8 + kn];
            float T6 = TR[6 * 8 + kn], T7 = TR[7 * 8 + kn];
            for (int j = 0; j < 64; ++j) {
                int t = c * 64 + j + 1;
                if (t <= 511) {
                    float4 a03 = *(const float4*)&alds[(t - 1) * 8];
                    float4 a47 = *(const float4*)&alds[(t - 1) * 8 + 4];
                    float v = a03.x + T0; int vi = 0; float nv;
                    nv = a03.y + T1; if (nv > v) { v = nv; vi = 1; }
                    nv = a03.z + T2; if (nv > v) { v = nv; vi = 2; }
                    nv = a03.w + T3; if (nv > v) { v = nv; vi = 3; }
                    nv = a47.x + T4; if (nv > v) { v = nv; vi = 4; }
                    nv = a47.y + T5; if (nv > v) { v = nv; vi = 5; }
                    nv = a47.z + T6; if (nv > v) { v = nv; vi = 6; }
                    nv = a47.w + T7; if (nv > v) { v = nv; vi = 7; }
                    bpb[t * 8 + kn] = (unsigned char)vi;
                }
            }
        }
        asm volatile("" ::: "memory");

        // Phase A: lane l composes bp maps for t in [8l+1, 8l+8]
        int t0 = lane * 8;
        unsigned rw[16];
#pragma unroll
        for (int j = 0; j < 8; ++j) {
            int t = t0 + 1 + j;
            if (t <= 511) { rw[2 * j] = bpw[t * 2]; rw[2 * j + 1] = bpw[t * 2 + 1]; }
            else          { rw[2 * j] = 0x03020100u; rw[2 * j + 1] = 0x07060504u; }
        }
        unsigned sv[8];
#pragma unroll
        for (int i = 0; i < 8; ++i) sv[i] = i;
#pragma unroll
        for (int j = 7; j >= 0; --j) {
            unsigned d0 = rw[2 * j], d1 = rw[2 * j + 1];
#pragma unroll
            for (int i = 0; i < 8; ++i) {
                unsigned s = sv[i];
                unsigned d = (s < 4) ? d0 : d1;
                sv[i] = (d >> (8 * (s & 3))) & 0xffu;
            }
        }
        fmapw[lane][0] = sv[0] | (sv[1] << 8) | (sv[2] << 16) | (sv[3] << 24);
        fmapw[lane][1] = sv[4] | (sv[5] << 8) | (sv[6] << 16) | (sv[7] << 24);
        asm volatile("" ::: "memory");

        // Phase B: lane 0 walks 64 chunk maps
        if (lane == 0) {
            unsigned cur = (unsigned)last_;
            for (int l = 63; l >= 0; --l) {
                unsigned d = (cur < 4) ? fmapw[l][0] : fmapw[l][1];
                cur = (d >> (8 * (cur & 3))) & 0xffu;
                bnd[l] = (unsigned char)cur;
            }
        }
        asm volatile("" ::: "memory");

        // Phase C: expand within chunk, write tags
        int off = h * 8;
        float* otag = out_tags + b * (3 * TT) + h * TT;
        unsigned curr = (lane == 63) ? (unsigned)last_ : (unsigned)bnd[lane + 1];
#pragma unroll
        for (int j = 7; j >= 0; --j) {
            unsigned d = (curr < 4) ? rw[2 * j] : rw[2 * j + 1];
            curr = (d >> (8 * (curr & 3))) & 0xffu;
            otag[t0 + j] = (float)((int)curr + off);
        }
    } else {
        // ========= CRF wave: octet-replicated multiplicative LSE =========
        float E0 = __expf(TR[(p ^ 0) * 8 + p]), E1 = __expf(TR[(p ^ 1) * 8 + p]);
        float E2 = __expf(TR[(p ^ 2) * 8 + p]), E3 = __expf(TR[(p ^ 3) * 8 + p]);
        float E4 = __expf(TR[(p ^ 7) * 8 + p]), E5 = __expf(TR[(p ^ 6) * 8 + p]);
        float E6 = __expf(TR[(p ^ 5) * 8 + p]), E7 = __expf(TR[(p ^ 4) * 8 + p]);

        float a0 = llds[p];
        float c0 = bcast8(a0, lane);
        float S  = __expf(a0 - c0);               // bounded: e^{a-a0}
        float Mc = c0;

        // step: gather current S; S' = (sum_j r_j E_j) * F; renorm every 4
#define LSTEP(t, F_, RN)                                                       \
    {                                                                          \
        if (RN) {                                                              \
            float sref = bcast8(S, lane);                                      \
            float gg = __logf(sref);                                           \
            S *= __expf(-gg);                                                  \
            Mc += gg;                                                          \
        }                                                                      \
        float r0, r1, r2, r3, r4, r5, r6, r7;                                  \
        GATHER8(S, r0, r1, r2, r3, r4, r5, r6, r7)                             \
        float p0 = r0 * E0, p1 = r1 * E1, p2 = r2 * E2, p3 = r3 * E3;          \
        float p4 = r4 * E4, p5 = r5 * E5, p6 = r6 * E6, p7 = r7 * E7;          \
        float ss = ((p0 + p1) + (p2 + p3)) + ((p4 + p5) + (p6 + p7));          \
        float Sn = ss * (F_);                                                  \
        S = ((t) < len) ? Sn : S;                                              \
    }

        for (int c = 0; c < 15; ++c) {            // t in [1+32c, 32+32c]
            int tb = 1 + 32 * c;
            float F[32];
#pragma unroll
            for (int j = 0; j < 32; ++j) F[j] = llds[(tb + j) * 8 + p];
#pragma unroll
            for (int j = 0; j < 32; ++j) F[j] = __expf(F[j]);
            __builtin_amdgcn_sched_barrier(0);
#pragma unroll
            for (int j = 0; j < 32; ++j) LSTEP(tb + j, F[j], (j & 3) == 0)
        }
        {   // epilogue: t = 481..511
            float F[31];
#pragma unroll
            for (int j = 0; j < 31; ++j) F[j] = llds[(481 + j) * 8 + p];
#pragma unroll
            for (int j = 0; j < 31; ++j) F[j] = __expf(F[j]);
            __builtin_amdgcn_sched_barrier(0);
#pragma unroll
            for (int j = 0; j < 31; ++j) LSTEP(481 + j, F[j], (j & 3) == 0)
        }
#undef LSTEP

        // logZ = Mc + log(sum over 8 states) -- within-octet DPP sum
        float s1 = S + DPPF(S, 0xB1);
        float s2 = s1 + DPPF(s1, 0x4E);
        float sum8 = s2 + DPPF(s2, 0x141);
        float logZ = Mc + __logf(sum8);

        // emit + transition scores (lane-parallel over t, 64 lanes)
        const int* lab = labels + b * (3 * TT) + h * TT;
        int off = h * 8;
        float sc = 0.f;
#pragma unroll
        for (int j = 0; j < 8; ++j) {
            int t = lane + 64 * j;
            if (t < len) {
                int tg = lab[t] - off;
                sc += llds[t * 8 + tg];
                if (t >= 1) {
                    int tp = lab[t - 1] - off;
                    sc += TR[tp * 8 + tg];
                }
            }
        }
#pragma unroll
        for (int d = 1; d <= 32; d <<= 1) sc += __shfl_xor(sc, d);

        if (lane == 0) partial[blk] = logZ - sc;
    }
}

// ---------------------------------------------------------------------------
// Kernel 3: deterministic loss reduction (192 partials -> scalar)
// ---------------------------------------------------------------------------
__global__ __launch_bounds__(64) void loss_reduce(
    const float* __restrict__ partial, float* __restrict__ out_loss)
{
    int lane = threadIdx.x;
    float s = partial[lane] + partial[lane + 64] + partial[lane + 128];
#pragma unroll
    for (int d = 1; d <= 32; d <<= 1) s += __shfl_xor(s, d);
    if (lane == 0) *out_loss = s;
}

// ---------------------------------------------------------------------------
extern "C" void kernel_launch(void* const* d_in, const int* in_sizes, int n_in,
                              void* d_out, int out_size, void* d_ws, size_t ws_size,
                              hipStream_t stream) {
    const float* enc    = (const float*)d_in[0];
    const int*   labels = (const int*)d_in[1];
    const int*   lens   = (const int*)d_in[2];
    const float* Wt     = (const float*)d_in[3];
    const float* bt     = (const float*)d_in[4];
    const float* Wp     = (const float*)d_in[5];
    const float* bpv    = (const float*)d_in[6];
    const float* Wm     = (const float*)d_in[7];
    const float* bm     = (const float*)d_in[8];
    const float* tr_t   = (const float*)d_in[9];
    const float* tr_p   = (const float*)d_in[10];
    const float* tr_m   = (const float*)d_in[11];

    float* out = (float*)d_out;
    float* lpart = (float*)d_ws;   // 192 floats

    gemm_heads<<<ROWS / 64, 256, 0, stream>>>(enc, Wt, bt, Wp, bpv, Wm, bm, out);
    crf_vit<<<192, 128, 0, stream>>>(out, labels, lens, tr_t, tr_p, tr_m,
                                     out + TAGS_OFF, lpart);
    loss_reduce<<<1, 64, 0, stream>>>(lpart, out + LOSS_OFF);
}